// Round 10
// baseline (282.398 us; speedup 1.0000x reference)
//
#include <hip/hip_runtime.h>
#include <math.h>

#define THREADS 256
#define NBLK 1024

typedef float f2v __attribute__((ext_vector_type(2)));
typedef float f4v __attribute__((ext_vector_type(4)));

// ---- codebook: fp32 levels exactly as numpy float32 computes them ----
static constexpr float kLvl[16] = {
    0.0f      / 0.75f, 0.015625f / 0.75f, 0.03125f / 0.75f, 0.046875f / 0.75f,
    0.0625f   / 0.75f, 0.09375f  / 0.75f, 0.125f   / 0.75f, 0.140625f / 0.75f,
    0.1875f   / 0.75f, 0.25f     / 0.75f, 0.28125f / 0.75f, 0.375f    / 0.75f,
    0.5f      / 0.75f, 0.515625f / 0.75f, 0.5625f  / 0.75f, 0.75f     / 0.75f,
};
// exact f64 midpoints of adjacent f32 levels: strict a>mid == numpy f32 argmin (Sterbenz)
static constexpr double kMid[15] = {
    ((double)kLvl[0]  + (double)kLvl[1])  * 0.5, ((double)kLvl[1]  + (double)kLvl[2])  * 0.5,
    ((double)kLvl[2]  + (double)kLvl[3])  * 0.5, ((double)kLvl[3]  + (double)kLvl[4])  * 0.5,
    ((double)kLvl[4]  + (double)kLvl[5])  * 0.5, ((double)kLvl[5]  + (double)kLvl[6])  * 0.5,
    ((double)kLvl[6]  + (double)kLvl[7])  * 0.5, ((double)kLvl[7]  + (double)kLvl[8])  * 0.5,
    ((double)kLvl[8]  + (double)kLvl[9])  * 0.5, ((double)kLvl[9]  + (double)kLvl[10]) * 0.5,
    ((double)kLvl[10] + (double)kLvl[11]) * 0.5, ((double)kLvl[11] + (double)kLvl[12]) * 0.5,
    ((double)kLvl[12] + (double)kLvl[13]) * 0.5, ((double)kLvl[13] + (double)kLvl[14]) * 0.5,
    ((double)kLvl[14] + (double)kLvl[15]) * 0.5,
};

__device__ __forceinline__ float tree64(float v) {
    #pragma unroll
    for (int m = 1; m <= 32; m <<= 1)
        v += __shfl_xor(v, m, 64);
    return v;
}

__device__ __forceinline__ float sgpr_bcast(float x) {
    return __uint_as_float(__builtin_amdgcn_readfirstlane(__float_as_uint(x)));
}

// X-macros over (leaf-group g, k-step)
#define K15(OP,G) OP(G,1) OP(G,2) OP(G,3) OP(G,4) OP(G,5) OP(G,6) OP(G,7) \
                  OP(G,8) OP(G,9) OP(G,10) OP(G,11) OP(G,12) OP(G,13) OP(G,14) OP(G,15)
#define K16(OP,G) OP(G,0) K15(OP,G)
#define ALLGK(OP) K16(OP,0) K16(OP,1)

// named-scalar select chain (verified round 7): mean-sub + 15 cmp/cndmask + bfi
#define QSEL(V, RES) do {                                   \
    float _u  = (V) - mean;                                 \
    float _au = fabsf(_u);                                  \
    float _o  = c0;                                         \
    _o = (_au < t0)  ? _o : c1;                             \
    _o = (_au < t1)  ? _o : c2;                             \
    _o = (_au < t2)  ? _o : c3;                             \
    _o = (_au < t3)  ? _o : c4;                             \
    _o = (_au < t4)  ? _o : c5;                             \
    _o = (_au < t5)  ? _o : c6;                             \
    _o = (_au < t6)  ? _o : c7;                             \
    _o = (_au < t7)  ? _o : c8;                             \
    _o = (_au < t8)  ? _o : c9;                             \
    _o = (_au < t9)  ? _o : c10;                            \
    _o = (_au < t10) ? _o : c11;                            \
    _o = (_au < t11) ? _o : c12;                            \
    _o = (_au < t12) ? _o : c13;                            \
    _o = (_au < t13) ? _o : c14;                            \
    _o = (_au < t14) ? _o : c15;                            \
    RES = copysignf(_o, _u);                                \
} while (0)

// SGPR hoist of thresholds/levels (shared by both quantize paths)
#define HOIST_TC()                                                        \
    const float t0  = sgpr_bcast(sT[0]),  t1  = sgpr_bcast(sT[1]);        \
    const float t2  = sgpr_bcast(sT[2]),  t3  = sgpr_bcast(sT[3]);        \
    const float t4  = sgpr_bcast(sT[4]),  t5  = sgpr_bcast(sT[5]);        \
    const float t6  = sgpr_bcast(sT[6]),  t7  = sgpr_bcast(sT[7]);        \
    const float t8  = sgpr_bcast(sT[8]),  t9  = sgpr_bcast(sT[9]);        \
    const float t10 = sgpr_bcast(sT[10]), t11 = sgpr_bcast(sT[11]);       \
    const float t12 = sgpr_bcast(sT[12]), t13 = sgpr_bcast(sT[13]);       \
    const float t14 = sgpr_bcast(sT[14]);                                 \
    const float c0  = sgpr_bcast(sC[0]),  c1  = sgpr_bcast(sC[1]);        \
    const float c2  = sgpr_bcast(sC[2]),  c3  = sgpr_bcast(sC[3]);        \
    const float c4  = sgpr_bcast(sC[4]),  c5  = sgpr_bcast(sC[5]);        \
    const float c6  = sgpr_bcast(sC[6]),  c7  = sgpr_bcast(sC[7]);        \
    const float c8  = sgpr_bcast(sC[8]),  c9  = sgpr_bcast(sC[9]);        \
    const float c10 = sgpr_bcast(sC[10]), c11 = sgpr_bcast(sC[11]);       \
    const float c12 = sgpr_bcast(sC[12]), c13 = sgpr_bcast(sC[13]);       \
    const float c14 = sgpr_bcast(sC[14]), c15 = sgpr_bcast(sC[15]);

// threshold binary search (verified): smallest f32 u>=0 whose IEEE f32 chain
// value u/sd -> /alpha -> clip exceeds kMid[i]
#define THRESH_SETUP(TID)                                                 \
    if ((TID) < 15) {                                                     \
        const double mid = kMid[(TID)];                                   \
        unsigned lo = 0u, hi = 0x7F800000u;                               \
        while (lo < hi) {                                                 \
            unsigned m = (lo + hi) >> 1;                                  \
            float uu = __uint_as_float(m);                                \
            float y  = uu / sd;                                           \
            float x  = y / al;                                            \
            float xc = fminf(x, 1.0f);                                    \
            if ((double)xc > mid) hi = m; else lo = m + 1;                \
        }                                                                 \
        sT[(TID)] = __uint_as_float(lo);                                  \
    } else if ((TID) < 31) {                                              \
        sC[(TID) - 15] = kLvl[(TID) - 15] * al;                           \
    } else if ((TID) == 31) {                                             \
        sC[0] = 0.0f;                                                     \
    }

// =====================================================================
// Fused single-pass kernel, software grid barrier, occupancy PINNED at
// 4 waves/EU (amdgpu_waves_per_eu(4,4)) so the allocator cannot spill
// the payload to chase occupancy (round-9 failure: VGPR 76 + scratch).
// 1024 blocks x 256 threads x 64 elems/thread = 2^24, all in registers.
// Lane map: group j=t>>2 (4 lanes) handles leaves {2j, 2j+1}; lane q=t&3
// owns numpy accs {2q,2q+1} per leaf via f2v loads. Pairwise tree:
// lane (x+y) + xor1/xor2 (in-leaf) + L0+L1 (adjacent leaf pair) +
// xor4..32 (wave = 32 leaves) + LDS (block = 128 leaves) — bit-exact.
// Co-residency: 4 blocks/CU x 256 CU = 1024 = grid, guaranteed by the
// pinned waves/EU + 512 B LDS. Counters zeroed per launch by memset.
// =====================================================================
__global__ __launch_bounds__(THREADS)
__attribute__((amdgpu_waves_per_eu(4, 4)))
void fused_all(const float* __restrict__ w,
               float* __restrict__ out,
               const float* __restrict__ alpha_ptr,
               int* __restrict__ cnt,
               float* __restrict__ wsum,
               float* __restrict__ wsq) {
    #pragma clang fp contract(off)
    const int t  = threadIdx.x;
    const int bx = blockIdx.x;

    __shared__ float sh[4];
    __shared__ float sMean, sSd;
    __shared__ float sT[15], sC[16];

    // block = 16384 floats = 128 leaves; group j = t>>2 owns leaves {2j,2j+1}
    const long long base = (long long)bx * 16384
                         + (long long)(t >> 2) * 256 + (long long)(t & 3) * 2;
    const f2v* pw = (const f2v*)(w + base);

    // ---- payload: 32 named f2v = 64 floats ----
    #define DECLV(G,K) f2v v##G##_##K = pw[G*64 + K*4];
    ALLGK(DECLV)
    #undef DECLV

    // ---- phase 1: global sum (numpy pairwise tree) ----
    {
        f2v a0 = v0_0, a1 = v1_0;
        #define ACC1(G,K) a##G += v##G##_##K;
        K15(ACC1,0) K15(ACC1,1)
        #undef ACC1
        float s0 = a0.x + a0.y, s1 = a1.x + a1.y;
        float L0 = s0 + __shfl_xor(s0, 1, 64); L0 = L0 + __shfl_xor(L0, 2, 64);
        float L1 = s1 + __shfl_xor(s1, 1, 64); L1 = L1 + __shfl_xor(L1, 2, 64);
        float nd = L0 + L1;                      // adjacent leaf pair {2j,2j+1}
        nd = nd + __shfl_xor(nd, 4, 64);
        nd = nd + __shfl_xor(nd, 8, 64);
        nd = nd + __shfl_xor(nd, 16, 64);
        nd = nd + __shfl_xor(nd, 32, 64);        // wave = 32 leaves
        if ((t & 63) == 0) sh[t >> 6] = nd;
    }
    __syncthreads();
    if (t == 0) {
        float p = (sh[0] + sh[1]) + (sh[2] + sh[3]);   // block = 128 leaves
        __hip_atomic_store(&wsum[bx], p, __ATOMIC_RELAXED, __HIP_MEMORY_SCOPE_AGENT);
        __hip_atomic_fetch_add(&cnt[0], 1, __ATOMIC_RELEASE, __HIP_MEMORY_SCOPE_AGENT);
        while (__hip_atomic_load(&cnt[0], __ATOMIC_ACQUIRE, __HIP_MEMORY_SCOPE_AGENT) < NBLK)
            __builtin_amdgcn_s_sleep(2);
    }
    __syncthreads();

    // ---- global mean: exact tree over 1024 partials (all 256 threads) ----
    {
        float p0 = __hip_atomic_load(&wsum[4*t+0], __ATOMIC_RELAXED, __HIP_MEMORY_SCOPE_AGENT);
        float p1 = __hip_atomic_load(&wsum[4*t+1], __ATOMIC_RELAXED, __HIP_MEMORY_SCOPE_AGENT);
        float p2 = __hip_atomic_load(&wsum[4*t+2], __ATOMIC_RELAXED, __HIP_MEMORY_SCOPE_AGENT);
        float p3 = __hip_atomic_load(&wsum[4*t+3], __ATOMIC_RELAXED, __HIP_MEMORY_SCOPE_AGENT);
        float g = (p0 + p1) + (p2 + p3);
        g = tree64(g);
        if ((t & 63) == 0) sh[t >> 6] = g;
        __syncthreads();
        if (t == 0) sMean = ((sh[0] + sh[1]) + (sh[2] + sh[3])) / 16777216.0f;
        __syncthreads();
    }
    const float mean = sgpr_bcast(sMean);

    // ---- phase 2: sum of (w-mean)^2 from registers ----
    {
        f2v m2; m2.x = mean; m2.y = mean;
        f2v d;
        d = v0_0 - m2; f2v q0  = d * d;
        d = v1_0 - m2; f2v q1v = d * d;
        #define ACC2_0(G,K) d = v##G##_##K - m2; q0  += d * d;
        #define ACC2_1(G,K) d = v##G##_##K - m2; q1v += d * d;
        K15(ACC2_0,0) K15(ACC2_1,1)
        #undef ACC2_0
        #undef ACC2_1
        float s0 = q0.x + q0.y, s1 = q1v.x + q1v.y;
        float L0 = s0 + __shfl_xor(s0, 1, 64); L0 = L0 + __shfl_xor(L0, 2, 64);
        float L1 = s1 + __shfl_xor(s1, 1, 64); L1 = L1 + __shfl_xor(L1, 2, 64);
        float nd = L0 + L1;
        nd = nd + __shfl_xor(nd, 4, 64);
        nd = nd + __shfl_xor(nd, 8, 64);
        nd = nd + __shfl_xor(nd, 16, 64);
        nd = nd + __shfl_xor(nd, 32, 64);
        if ((t & 63) == 0) sh[t >> 6] = nd;
    }
    __syncthreads();
    if (t == 0) {
        float p = (sh[0] + sh[1]) + (sh[2] + sh[3]);
        __hip_atomic_store(&wsq[bx], p, __ATOMIC_RELAXED, __HIP_MEMORY_SCOPE_AGENT);
        __hip_atomic_fetch_add(&cnt[1], 1, __ATOMIC_RELEASE, __HIP_MEMORY_SCOPE_AGENT);
        while (__hip_atomic_load(&cnt[1], __ATOMIC_ACQUIRE, __HIP_MEMORY_SCOPE_AGENT) < NBLK)
            __builtin_amdgcn_s_sleep(2);
    }
    __syncthreads();

    // ---- sd + thresholds ----
    {
        float p0 = __hip_atomic_load(&wsq[4*t+0], __ATOMIC_RELAXED, __HIP_MEMORY_SCOPE_AGENT);
        float p1 = __hip_atomic_load(&wsq[4*t+1], __ATOMIC_RELAXED, __HIP_MEMORY_SCOPE_AGENT);
        float p2 = __hip_atomic_load(&wsq[4*t+2], __ATOMIC_RELAXED, __HIP_MEMORY_SCOPE_AGENT);
        float p3 = __hip_atomic_load(&wsq[4*t+3], __ATOMIC_RELAXED, __HIP_MEMORY_SCOPE_AGENT);
        float g = (p0 + p1) + (p2 + p3);
        g = tree64(g);
        if ((t & 63) == 0) sh[t >> 6] = g;
        __syncthreads();
        if (t == 0) sSd = sqrtf(((sh[0] + sh[1]) + (sh[2] + sh[3])) / 16777215.0f);
        __syncthreads();
    }
    {
        const float sd = sSd;
        const float al = alpha_ptr[0];
        THRESH_SETUP(t)
    }
    __syncthreads();

    HOIST_TC()

    // ---- phase 3: quantize from registers, store ----
    f2v* po = (f2v*)(out + base);
    #define QST(G,K) { f2v r;                                      \
        QSEL(v##G##_##K.x, r.x); QSEL(v##G##_##K.y, r.y);          \
        __builtin_nontemporal_store(r, &po[G*64 + K*4]); }
    ALLGK(QST)
    #undef QST
}

// =====================================================================
// Fallback (round-7 verified 3-kernel pipeline) for n != 2^24
// =====================================================================
template<int PASS>
__global__ __launch_bounds__(THREADS) void leaf_pass(const float* __restrict__ w,
                                                     const float* __restrict__ bprev,
                                                     float* __restrict__ bout,
                                                     long long n, int nb) {
    #pragma clang fp contract(off)
    __shared__ float ws4[4];
    __shared__ float smean;
    float mean = 0.0f;
    if (PASS == 1) {
        int i0 = threadIdx.x * 8;
        float v = 0.0f;
        if (i0 + 7 < nb) {
            const float* p = bprev + i0;
            v = ((p[0] + p[1]) + (p[2] + p[3])) + ((p[4] + p[5]) + (p[6] + p[7]));
        }
        v = tree64(v);
        if ((threadIdx.x & 63) == 0) ws4[threadIdx.x >> 6] = v;
        __syncthreads();
        if (threadIdx.x == 0)
            smean = ((ws4[0] + ws4[1]) + (ws4[2] + ws4[3])) / (float)n;
        __syncthreads();
        mean = smean;
    }
    const long long base = (long long)blockIdx.x * 8192
                         + (long long)(threadIdx.x >> 2) * 128
                         + (long long)(threadIdx.x & 3) * 2;
    const f2v* p = (const f2v*)(w + base);
    float s0, s1;
    {
        f2v a = p[0];
        if (PASS == 1) { float x = a.x - mean, y = a.y - mean; s0 = x * x; s1 = y * y; }
        else           { s0 = a.x; s1 = a.y; }
    }
    #pragma unroll
    for (int t = 1; t < 16; ++t) {
        f2v a = p[4 * t];
        if (PASS == 1) { float x = a.x - mean, y = a.y - mean; s0 += x * x; s1 += y * y; }
        else           { s0 += a.x; s1 += a.y; }
    }
    float s = s0 + s1;
    s = tree64(s);
    if ((threadIdx.x & 63) == 0) ws4[threadIdx.x >> 6] = s;
    __syncthreads();
    if (threadIdx.x == 0)
        bout[blockIdx.x] = (ws4[0] + ws4[1]) + (ws4[2] + ws4[3]);
}

__global__ __launch_bounds__(THREADS) void quantize_k(const f4v* __restrict__ w4,
                                                      f4v* __restrict__ o4,
                                                      const float* __restrict__ bout0,
                                                      const float* __restrict__ bout1,
                                                      const float* __restrict__ alpha_ptr,
                                                      long long n, int nb) {
    #pragma clang fp contract(off)
    __shared__ float wsA[4], wsB[4];
    __shared__ float sP[2];
    __shared__ float sT[15];
    __shared__ float sC[16];
    {
        int i0 = threadIdx.x * 8;
        float v = 0.0f, u = 0.0f;
        if (i0 + 7 < nb) {
            const float* p0 = bout0 + i0;
            const float* p1 = bout1 + i0;
            v = ((p0[0] + p0[1]) + (p0[2] + p0[3])) + ((p0[4] + p0[5]) + (p0[6] + p0[7]));
            u = ((p1[0] + p1[1]) + (p1[2] + p1[3])) + ((p1[4] + p1[5]) + (p1[6] + p1[7]));
        }
        v = tree64(v);
        u = tree64(u);
        if ((threadIdx.x & 63) == 0) { wsA[threadIdx.x >> 6] = v; wsB[threadIdx.x >> 6] = u; }
        __syncthreads();
        if (threadIdx.x == 0) {
            sP[0] = ((wsA[0] + wsA[1]) + (wsA[2] + wsA[3])) / (float)n;
            sP[1] = sqrtf(((wsB[0] + wsB[1]) + (wsB[2] + wsB[3])) / (float)(n - 1));
        }
        __syncthreads();
    }
    {
        const float sd = sP[1];
        const float al = alpha_ptr[0];
        THRESH_SETUP(threadIdx.x)
    }
    __syncthreads();

    const float mean = sgpr_bcast(sP[0]);
    HOIST_TC()

    long long n4     = n >> 2;
    long long tid    = (long long)blockIdx.x * THREADS + threadIdx.x;
    long long stride = (long long)gridDim.x * THREADS;

    long long i = tid;
    for (; i + stride < n4; i += 2 * stride) {
        f4v a = w4[i];
        f4v b = w4[i + stride];
        f4v ra, rb;
        QSEL(a.x, ra.x); QSEL(a.y, ra.y); QSEL(a.z, ra.z); QSEL(a.w, ra.w);
        QSEL(b.x, rb.x); QSEL(b.y, rb.y); QSEL(b.z, rb.z); QSEL(b.w, rb.w);
        __builtin_nontemporal_store(ra, &o4[i]);
        __builtin_nontemporal_store(rb, &o4[i + stride]);
    }
    for (; i < n4; i += stride) {
        f4v a = w4[i];
        f4v ra;
        QSEL(a.x, ra.x); QSEL(a.y, ra.y); QSEL(a.z, ra.z); QSEL(a.w, ra.w);
        __builtin_nontemporal_store(ra, &o4[i]);
    }
}

extern "C" void kernel_launch(void* const* d_in, const int* in_sizes, int n_in,
                              void* d_out, int out_size, void* d_ws, size_t ws_size,
                              hipStream_t stream) {
    const float* w     = (const float*)d_in[0];
    const float* alpha = (const float*)d_in[1];
    float* out = (float*)d_out;
    long long n = (long long)in_sizes[0];          // 16777216 = 2^24

    size_t need = 2 * sizeof(int) + (size_t)(2 * NBLK) * sizeof(float);
    if (n == (1LL << 24) && ws_size >= need) {
        int*   cnt  = (int*)d_ws;                  // [cnt0, cnt1]
        float* wsum = (float*)d_ws + 2;            // 1024 partials (sum)
        float* wsq  = wsum + NBLK;                 // 1024 partials (sumsq)
        hipMemsetAsync(cnt, 0, 2 * sizeof(int), stream);   // reset barrier counters
        fused_all<<<NBLK, THREADS, 0, stream>>>(w, out, alpha, cnt, wsum, wsq);
    } else {
        int nblk = (int)(n >> 13);
        float* bout0 = (float*)d_ws;
        float* bout1 = bout0 + nblk;
        leaf_pass<0><<<nblk, THREADS, 0, stream>>>(w, nullptr, bout0, n, nblk);
        leaf_pass<1><<<nblk, THREADS, 0, stream>>>(w, bout0, bout1, n, nblk);
        quantize_k<<<2048, THREADS, 0, stream>>>((const f4v*)w, (f4v*)out,
                                                 bout0, bout1, alpha, n, nblk);
    }
}

// Round 11
// 57.641 us; speedup vs baseline: 4.8992x; 4.8992x over previous
//
#include <hip/hip_runtime.h>
#include <math.h>

#define THREADS 256

typedef float f2v __attribute__((ext_vector_type(2)));
typedef float f4v __attribute__((ext_vector_type(4)));

// ---- codebook: fp32 levels exactly as numpy float32 computes them ----
static constexpr float kLvl[16] = {
    0.0f      / 0.75f, 0.015625f / 0.75f, 0.03125f / 0.75f, 0.046875f / 0.75f,
    0.0625f   / 0.75f, 0.09375f  / 0.75f, 0.125f   / 0.75f, 0.140625f / 0.75f,
    0.1875f   / 0.75f, 0.25f     / 0.75f, 0.28125f / 0.75f, 0.375f    / 0.75f,
    0.5f      / 0.75f, 0.515625f / 0.75f, 0.5625f  / 0.75f, 0.75f     / 0.75f,
};
// exact f64 midpoints of adjacent f32 levels: strict a>mid == numpy f32 argmin (Sterbenz)
static constexpr double kMid[15] = {
    ((double)kLvl[0]  + (double)kLvl[1])  * 0.5, ((double)kLvl[1]  + (double)kLvl[2])  * 0.5,
    ((double)kLvl[2]  + (double)kLvl[3])  * 0.5, ((double)kLvl[3]  + (double)kLvl[4])  * 0.5,
    ((double)kLvl[4]  + (double)kLvl[5])  * 0.5, ((double)kLvl[5]  + (double)kLvl[6])  * 0.5,
    ((double)kLvl[6]  + (double)kLvl[7])  * 0.5, ((double)kLvl[7]  + (double)kLvl[8])  * 0.5,
    ((double)kLvl[8]  + (double)kLvl[9])  * 0.5, ((double)kLvl[9]  + (double)kLvl[10]) * 0.5,
    ((double)kLvl[10] + (double)kLvl[11]) * 0.5, ((double)kLvl[11] + (double)kLvl[12]) * 0.5,
    ((double)kLvl[12] + (double)kLvl[13]) * 0.5, ((double)kLvl[13] + (double)kLvl[14]) * 0.5,
    ((double)kLvl[14] + (double)kLvl[15]) * 0.5,
};

__device__ __forceinline__ float tree64(float v) {
    #pragma unroll
    for (int m = 1; m <= 32; m <<= 1)
        v += __shfl_xor(v, m, 64);
    return v;
}

__device__ __forceinline__ float sgpr_bcast(float x) {
    return __uint_as_float(__builtin_amdgcn_readfirstlane(__float_as_uint(x)));
}

// named-scalar select chain (verified round 7): mean-sub + 15 cmp/cndmask + bfi
#define QSEL(V, RES) do {                                   \
    float _u  = (V) - mean;                                 \
    float _au = fabsf(_u);                                  \
    float _o  = c0;                                         \
    _o = (_au < t0)  ? _o : c1;                             \
    _o = (_au < t1)  ? _o : c2;                             \
    _o = (_au < t2)  ? _o : c3;                             \
    _o = (_au < t3)  ? _o : c4;                             \
    _o = (_au < t4)  ? _o : c5;                             \
    _o = (_au < t5)  ? _o : c6;                             \
    _o = (_au < t6)  ? _o : c7;                             \
    _o = (_au < t7)  ? _o : c8;                             \
    _o = (_au < t8)  ? _o : c9;                             \
    _o = (_au < t9)  ? _o : c10;                            \
    _o = (_au < t10) ? _o : c11;                            \
    _o = (_au < t11) ? _o : c12;                            \
    _o = (_au < t12) ? _o : c13;                            \
    _o = (_au < t13) ? _o : c14;                            \
    _o = (_au < t14) ? _o : c15;                            \
    RES = copysignf(_o, _u);                                \
} while (0)

// SGPR hoist of uniforms from LDS staging (verified round 7)
#define HOIST_TC(SRC)                                                     \
    const float t0  = sgpr_bcast(SRC[1]),  t1  = sgpr_bcast(SRC[2]);      \
    const float t2  = sgpr_bcast(SRC[3]),  t3  = sgpr_bcast(SRC[4]);      \
    const float t4  = sgpr_bcast(SRC[5]),  t5  = sgpr_bcast(SRC[6]);      \
    const float t6  = sgpr_bcast(SRC[7]),  t7  = sgpr_bcast(SRC[8]);      \
    const float t8  = sgpr_bcast(SRC[9]),  t9  = sgpr_bcast(SRC[10]);     \
    const float t10 = sgpr_bcast(SRC[11]), t11 = sgpr_bcast(SRC[12]);     \
    const float t12 = sgpr_bcast(SRC[13]), t13 = sgpr_bcast(SRC[14]);     \
    const float t14 = sgpr_bcast(SRC[15]);                                \
    const float c0  = sgpr_bcast(SRC[16]), c1  = sgpr_bcast(SRC[17]);     \
    const float c2  = sgpr_bcast(SRC[18]), c3  = sgpr_bcast(SRC[19]);     \
    const float c4  = sgpr_bcast(SRC[20]), c5  = sgpr_bcast(SRC[21]);     \
    const float c6  = sgpr_bcast(SRC[22]), c7  = sgpr_bcast(SRC[23]);     \
    const float c8  = sgpr_bcast(SRC[24]), c9  = sgpr_bcast(SRC[25]);     \
    const float c10 = sgpr_bcast(SRC[26]), c11 = sgpr_bcast(SRC[27]);     \
    const float c12 = sgpr_bcast(SRC[28]), c13 = sgpr_bcast(SRC[29]);     \
    const float c14 = sgpr_bcast(SRC[30]), c15 = sgpr_bcast(SRC[31]);

// ---- leaf pass (verified rounds 4-7 — ~6.1 TB/s).
// 4 lanes per 128-elem numpy leaf; lane r owns accs {2r,2r+1}; xor butterfly
// reproduces numpy's pairwise tree bit-exactly. Block = 64 leaves = 8192 elems.
template<int PASS>
__global__ __launch_bounds__(THREADS) void leaf_pass(const float* __restrict__ w,
                                                     const float* __restrict__ bprev,
                                                     float* __restrict__ bout,
                                                     long long n, int nb) {
    #pragma clang fp contract(off)
    __shared__ float ws4[4];
    __shared__ float smean;
    float mean = 0.0f;
    if (PASS == 1) {
        int i0 = threadIdx.x * 8;
        float v = 0.0f;
        if (i0 + 7 < nb) {
            const float* p = bprev + i0;
            v = ((p[0] + p[1]) + (p[2] + p[3])) + ((p[4] + p[5]) + (p[6] + p[7]));
        }
        v = tree64(v);
        if ((threadIdx.x & 63) == 0) ws4[threadIdx.x >> 6] = v;
        __syncthreads();
        if (threadIdx.x == 0)
            smean = ((ws4[0] + ws4[1]) + (ws4[2] + ws4[3])) / (float)n;
        __syncthreads();
        mean = smean;
    }
    const long long base = (long long)blockIdx.x * 8192
                         + (long long)(threadIdx.x >> 2) * 128
                         + (long long)(threadIdx.x & 3) * 2;
    const f2v* p = (const f2v*)(w + base);
    float s0, s1;
    {
        f2v a = p[0];
        if (PASS == 1) { float x = a.x - mean, y = a.y - mean; s0 = x * x; s1 = y * y; }
        else           { s0 = a.x; s1 = a.y; }
    }
    #pragma unroll
    for (int t = 1; t < 16; ++t) {
        f2v a = p[4 * t];
        if (PASS == 1) { float x = a.x - mean, y = a.y - mean; s0 += x * x; s1 += y * y; }
        else           { s0 += a.x; s1 += a.y; }
    }
    float s = s0 + s1;
    s = tree64(s);
    if ((threadIdx.x & 63) == 0) ws4[threadIdx.x >> 6] = s;
    __syncthreads();
    if (threadIdx.x == 0)
        bout[blockIdx.x] = (ws4[0] + ws4[1]) + (ws4[2] + ws4[3]);
}

// ---- finalize (1 block): exact-tree reduce partials -> mean, sd; binary-search
// the 15 u-space thresholds; emit params = [mean, T0..14, C0..15].
__global__ __launch_bounds__(THREADS) void finz(const float* __restrict__ bout0,
                                                const float* __restrict__ bout1,
                                                const float* __restrict__ alpha_ptr,
                                                long long n, int nb,
                                                float* __restrict__ params) {
    #pragma clang fp contract(off)
    __shared__ float wsA[4], wsB[4];
    __shared__ float sMean, sSd;
    {
        int i0 = threadIdx.x * 8;
        float v = 0.0f, u = 0.0f;
        if (i0 + 7 < nb) {
            const float* p0 = bout0 + i0;
            const float* p1 = bout1 + i0;
            v = ((p0[0] + p0[1]) + (p0[2] + p0[3])) + ((p0[4] + p0[5]) + (p0[6] + p0[7]));
            u = ((p1[0] + p1[1]) + (p1[2] + p1[3])) + ((p1[4] + p1[5]) + (p1[6] + p1[7]));
        }
        v = tree64(v);
        u = tree64(u);
        if ((threadIdx.x & 63) == 0) { wsA[threadIdx.x >> 6] = v; wsB[threadIdx.x >> 6] = u; }
        __syncthreads();
        if (threadIdx.x == 0) {
            sMean = ((wsA[0] + wsA[1]) + (wsA[2] + wsA[3])) / (float)n;
            sSd   = sqrtf(((wsB[0] + wsB[1]) + (wsB[2] + wsB[3])) / (float)(n - 1));
        }
        __syncthreads();
    }
    const float sd = sSd;
    const float al = alpha_ptr[0];
    const int t = threadIdx.x;
    if (t == 32) params[0] = sMean;
    if (t < 15) {
        // smallest f32 u >= 0 whose IEEE f32 chain value exceeds kMid[t]
        const double mid = kMid[t];
        unsigned lo = 0u, hi = 0x7F800000u;        // [+0, +inf]
        while (lo < hi) {
            unsigned m = (lo + hi) >> 1;
            float uu = __uint_as_float(m);
            float y  = uu / sd;                    // f32 IEEE div (matches numpy)
            float x  = y / al;                     // f32 IEEE div
            float xc = fminf(x, 1.0f);             // clip upper (abs domain)
            if ((double)xc > mid) hi = m; else lo = m + 1;
        }
        params[1 + t] = __uint_as_float(lo);
    } else if (t >= 16 && t < 32) {
        int i = t - 16;
        params[16 + i] = (i == 0) ? 0.0f : kLvl[i] * al;   // C[i], same bits as ref
    }
}

// ---- quantize: prologue = 32 uniform loads; stream = sub/abs/15 cmp+sel/bfi.
// Plain (cached) loads AND stores this round; unroll-4 for MLP.
__global__ __launch_bounds__(THREADS) void quantize_s(const f4v* __restrict__ w4,
                                                      f4v* __restrict__ o4,
                                                      const float* __restrict__ params,
                                                      long long n4) {
    #pragma clang fp contract(off)
    __shared__ float sp[32];
    if (threadIdx.x < 32) sp[threadIdx.x] = params[threadIdx.x];
    __syncthreads();
    const float mean = sgpr_bcast(sp[0]);
    HOIST_TC(sp)

    long long tid    = (long long)blockIdx.x * THREADS + threadIdx.x;
    long long stride = (long long)gridDim.x * THREADS;

    long long i = tid;
    for (; i + 3 * stride < n4; i += 4 * stride) {   // unroll-4: 4 f4v in flight
        f4v a = w4[i];
        f4v b = w4[i + stride];
        f4v c = w4[i + 2 * stride];
        f4v d = w4[i + 3 * stride];
        f4v ra, rb, rc, rd;
        QSEL(a.x, ra.x); QSEL(a.y, ra.y); QSEL(a.z, ra.z); QSEL(a.w, ra.w);
        QSEL(b.x, rb.x); QSEL(b.y, rb.y); QSEL(b.z, rb.z); QSEL(b.w, rb.w);
        QSEL(c.x, rc.x); QSEL(c.y, rc.y); QSEL(c.z, rc.z); QSEL(c.w, rc.w);
        QSEL(d.x, rd.x); QSEL(d.y, rd.y); QSEL(d.z, rd.z); QSEL(d.w, rd.w);
        o4[i]              = ra;
        o4[i + stride]     = rb;
        o4[i + 2 * stride] = rc;
        o4[i + 3 * stride] = rd;
    }
    for (; i < n4; i += stride) {                    // tail (unused at n = 2^24)
        f4v a = w4[i];
        f4v ra;
        QSEL(a.x, ra.x); QSEL(a.y, ra.y); QSEL(a.z, ra.z); QSEL(a.w, ra.w);
        o4[i] = ra;
    }
}

extern "C" void kernel_launch(void* const* d_in, const int* in_sizes, int n_in,
                              void* d_out, int out_size, void* d_ws, size_t ws_size,
                              hipStream_t stream) {
    const float* w     = (const float*)d_in[0];
    const float* alpha = (const float*)d_in[1];
    float* out = (float*)d_out;
    long long n = (long long)in_sizes[0];          // 16777216 = 2^24

    int nblk = (int)(n >> 13);                     // 8192 elems/block -> 2048 blocks
    float* bout0  = (float*)d_ws;                  // nblk partials (sum)
    float* bout1  = bout0 + nblk;                  // nblk partials (sumsq)
    float* params = bout1 + nblk;                  // 32 floats [mean, T0..14, C0..15]

    leaf_pass<0><<<nblk, THREADS, 0, stream>>>(w, nullptr, bout0, n, nblk);
    leaf_pass<1><<<nblk, THREADS, 0, stream>>>(w, bout0, bout1, n, nblk);
    finz<<<1, THREADS, 0, stream>>>(bout0, bout1, alpha, n, nblk, params);
    quantize_s<<<2048, THREADS, 0, stream>>>((const f4v*)w, (f4v*)out, params, n >> 2);
}

// Round 12
// 52.700 us; speedup vs baseline: 5.3586x; 1.0938x over previous
//
#include <hip/hip_runtime.h>
#include <math.h>

#define THREADS 256

typedef float f2v __attribute__((ext_vector_type(2)));
typedef float f4v __attribute__((ext_vector_type(4)));

// ---- codebook: fp32 levels exactly as numpy float32 computes them ----
static constexpr float kLvl[16] = {
    0.0f      / 0.75f, 0.015625f / 0.75f, 0.03125f / 0.75f, 0.046875f / 0.75f,
    0.0625f   / 0.75f, 0.09375f  / 0.75f, 0.125f   / 0.75f, 0.140625f / 0.75f,
    0.1875f   / 0.75f, 0.25f     / 0.75f, 0.28125f / 0.75f, 0.375f    / 0.75f,
    0.5f      / 0.75f, 0.515625f / 0.75f, 0.5625f  / 0.75f, 0.75f     / 0.75f,
};
// exact f64 midpoints of adjacent f32 levels: strict a>mid == numpy f32 argmin (Sterbenz)
static constexpr double kMid[15] = {
    ((double)kLvl[0]  + (double)kLvl[1])  * 0.5, ((double)kLvl[1]  + (double)kLvl[2])  * 0.5,
    ((double)kLvl[2]  + (double)kLvl[3])  * 0.5, ((double)kLvl[3]  + (double)kLvl[4])  * 0.5,
    ((double)kLvl[4]  + (double)kLvl[5])  * 0.5, ((double)kLvl[5]  + (double)kLvl[6])  * 0.5,
    ((double)kLvl[6]  + (double)kLvl[7])  * 0.5, ((double)kLvl[7]  + (double)kLvl[8])  * 0.5,
    ((double)kLvl[8]  + (double)kLvl[9])  * 0.5, ((double)kLvl[9]  + (double)kLvl[10]) * 0.5,
    ((double)kLvl[10] + (double)kLvl[11]) * 0.5, ((double)kLvl[11] + (double)kLvl[12]) * 0.5,
    ((double)kLvl[12] + (double)kLvl[13]) * 0.5, ((double)kLvl[13] + (double)kLvl[14]) * 0.5,
    ((double)kLvl[14] + (double)kLvl[15]) * 0.5,
};

__device__ __forceinline__ float tree64(float v) {
    #pragma unroll
    for (int m = 1; m <= 32; m <<= 1)
        v += __shfl_xor(v, m, 64);
    return v;
}

__device__ __forceinline__ float sgpr_bcast(float x) {
    return __uint_as_float(__builtin_amdgcn_readfirstlane(__float_as_uint(x)));
}

// named-scalar select chain (verified round 7): mean-sub + 15 cmp/cndmask + bfi
#define QSEL(V, RES) do {                                   \
    float _u  = (V) - mean;                                 \
    float _au = fabsf(_u);                                  \
    float _o  = c0;                                         \
    _o = (_au < t0)  ? _o : c1;                             \
    _o = (_au < t1)  ? _o : c2;                             \
    _o = (_au < t2)  ? _o : c3;                             \
    _o = (_au < t3)  ? _o : c4;                             \
    _o = (_au < t4)  ? _o : c5;                             \
    _o = (_au < t5)  ? _o : c6;                             \
    _o = (_au < t6)  ? _o : c7;                             \
    _o = (_au < t7)  ? _o : c8;                             \
    _o = (_au < t8)  ? _o : c9;                             \
    _o = (_au < t9)  ? _o : c10;                            \
    _o = (_au < t10) ? _o : c11;                            \
    _o = (_au < t11) ? _o : c12;                            \
    _o = (_au < t12) ? _o : c13;                            \
    _o = (_au < t13) ? _o : c14;                            \
    _o = (_au < t14) ? _o : c15;                            \
    RES = copysignf(_o, _u);                                \
} while (0)

// SGPR hoist from sT/sC LDS arrays (round-7 style, verified)
#define HOIST_TC()                                                        \
    const float t0  = sgpr_bcast(sT[0]),  t1  = sgpr_bcast(sT[1]);        \
    const float t2  = sgpr_bcast(sT[2]),  t3  = sgpr_bcast(sT[3]);        \
    const float t4  = sgpr_bcast(sT[4]),  t5  = sgpr_bcast(sT[5]);        \
    const float t6  = sgpr_bcast(sT[6]),  t7  = sgpr_bcast(sT[7]);        \
    const float t8  = sgpr_bcast(sT[8]),  t9  = sgpr_bcast(sT[9]);        \
    const float t10 = sgpr_bcast(sT[10]), t11 = sgpr_bcast(sT[11]);       \
    const float t12 = sgpr_bcast(sT[12]), t13 = sgpr_bcast(sT[13]);       \
    const float t14 = sgpr_bcast(sT[14]);                                 \
    const float c0  = sgpr_bcast(sC[0]),  c1  = sgpr_bcast(sC[1]);        \
    const float c2  = sgpr_bcast(sC[2]),  c3  = sgpr_bcast(sC[3]);        \
    const float c4  = sgpr_bcast(sC[4]),  c5  = sgpr_bcast(sC[5]);        \
    const float c6  = sgpr_bcast(sC[6]),  c7  = sgpr_bcast(sC[7]);        \
    const float c8  = sgpr_bcast(sC[8]),  c9  = sgpr_bcast(sC[9]);        \
    const float c10 = sgpr_bcast(sC[10]), c11 = sgpr_bcast(sC[11]);       \
    const float c12 = sgpr_bcast(sC[12]), c13 = sgpr_bcast(sC[13]);       \
    const float c14 = sgpr_bcast(sC[14]), c15 = sgpr_bcast(sC[15]);

// threshold binary search (verified): smallest f32 u>=0 whose IEEE f32 chain
// value u/sd -> /alpha -> clip exceeds kMid[i]
#define THRESH_SETUP(TID)                                                 \
    if ((TID) < 15) {                                                     \
        const double mid = kMid[(TID)];                                   \
        unsigned lo = 0u, hi = 0x7F800000u;                               \
        while (lo < hi) {                                                 \
            unsigned m = (lo + hi) >> 1;                                  \
            float uu = __uint_as_float(m);                                \
            float y  = uu / sd;                                           \
            float x  = y / al;                                            \
            float xc = fminf(x, 1.0f);                                    \
            if ((double)xc > mid) hi = m; else lo = m + 1;                \
        }                                                                 \
        sT[(TID)] = __uint_as_float(lo);                                  \
    } else if ((TID) < 31) {                                              \
        sC[(TID) - 15] = kLvl[(TID) - 15] * al;                           \
    } else if ((TID) == 31) {                                             \
        sC[0] = 0.0f;                                                     \
    }

// ---- leaf pass (verified rounds 4-7 — ~6 TB/s).
// 4 lanes per 128-elem numpy leaf; xor butterfly == numpy pairwise tree.
// Block = 64 leaves = 8192 elems. REV=1: XCD-matched reverse region map
// region = (b&7) + 8*((nb/8-1) - b/8) — same XCD (b%8 preserved), regions
// most recently touched by the PREVIOUS pass's late blocks come first
// (L2 warmth). Pure dispatch permutation: partials indexed by REGION.
template<int PASS, int REV>
__global__ __launch_bounds__(THREADS) void leaf_pass(const float* __restrict__ w,
                                                     const float* __restrict__ bprev,
                                                     float* __restrict__ bout,
                                                     long long n, int nb) {
    #pragma clang fp contract(off)
    __shared__ float ws4[4];
    __shared__ float smean;
    float mean = 0.0f;
    if (PASS == 1) {
        int i0 = threadIdx.x * 8;
        float v = 0.0f;
        if (i0 + 7 < nb) {
            const float* p = bprev + i0;
            v = ((p[0] + p[1]) + (p[2] + p[3])) + ((p[4] + p[5]) + (p[6] + p[7]));
        }
        v = tree64(v);
        if ((threadIdx.x & 63) == 0) ws4[threadIdx.x >> 6] = v;
        __syncthreads();
        if (threadIdx.x == 0)
            smean = ((ws4[0] + ws4[1]) + (ws4[2] + ws4[3])) / (float)n;
        __syncthreads();
        mean = smean;
    }
    int region = blockIdx.x;
    if (REV && (nb & 7) == 0) {
        int j = blockIdx.x >> 3;
        region = (blockIdx.x & 7) + 8 * ((nb >> 3) - 1 - j);
    }
    const long long base = (long long)region * 8192
                         + (long long)(threadIdx.x >> 2) * 128
                         + (long long)(threadIdx.x & 3) * 2;
    const f2v* p = (const f2v*)(w + base);
    float s0, s1;
    {
        f2v a = p[0];
        if (PASS == 1) { float x = a.x - mean, y = a.y - mean; s0 = x * x; s1 = y * y; }
        else           { s0 = a.x; s1 = a.y; }
    }
    #pragma unroll
    for (int t = 1; t < 16; ++t) {
        f2v a = p[4 * t];
        if (PASS == 1) { float x = a.x - mean, y = a.y - mean; s0 += x * x; s1 += y * y; }
        else           { s0 += a.x; s1 += a.y; }
    }
    float s = s0 + s1;
    s = tree64(s);
    if ((threadIdx.x & 63) == 0) ws4[threadIdx.x >> 6] = s;
    __syncthreads();
    if (threadIdx.x == 0)
        bout[region] = (ws4[0] + ws4[1]) + (ws4[2] + ws4[3]);
}

// ---- fused quantize (fast path, n = 2^24, nb = 2048): finalize prologue
// (verified round 7) + BLOCKED identity layout (block b -> region b, warm on
// the XCD that leaf1-reversed just touched) + 8 loads in flight + NT stores.
__global__ __launch_bounds__(THREADS) void quantize_b(const f4v* __restrict__ w4,
                                                      f4v* __restrict__ o4,
                                                      const float* __restrict__ bout0,
                                                      const float* __restrict__ bout1,
                                                      const float* __restrict__ alpha_ptr,
                                                      long long n, int nb) {
    #pragma clang fp contract(off)
    __shared__ float wsA[4], wsB[4];
    __shared__ float sP[2];
    __shared__ float sT[15];
    __shared__ float sC[16];
    {
        int i0 = threadIdx.x * 8;
        float v = 0.0f, u = 0.0f;
        if (i0 + 7 < nb) {
            const float* p0 = bout0 + i0;
            const float* p1 = bout1 + i0;
            v = ((p0[0] + p0[1]) + (p0[2] + p0[3])) + ((p0[4] + p0[5]) + (p0[6] + p0[7]));
            u = ((p1[0] + p1[1]) + (p1[2] + p1[3])) + ((p1[4] + p1[5]) + (p1[6] + p1[7]));
        }
        v = tree64(v);
        u = tree64(u);
        if ((threadIdx.x & 63) == 0) { wsA[threadIdx.x >> 6] = v; wsB[threadIdx.x >> 6] = u; }
        __syncthreads();
        if (threadIdx.x == 0) {
            sP[0] = ((wsA[0] + wsA[1]) + (wsA[2] + wsA[3])) / (float)n;
            sP[1] = sqrtf(((wsB[0] + wsB[1]) + (wsB[2] + wsB[3])) / (float)(n - 1));
        }
        __syncthreads();
    }
    {
        const float sd = sP[1];
        const float al = alpha_ptr[0];
        THRESH_SETUP(threadIdx.x)
    }
    __syncthreads();

    const float mean = sgpr_bcast(sP[0]);
    HOIST_TC()

    // block b covers f4v [b*2048, (b+1)*2048); thread t: base + k*256, k=0..7
    const long long base = (long long)blockIdx.x * 2048 + threadIdx.x;
    f4v a0 = w4[base];                  // 8 loads issued up front (MLP=8)
    f4v a1 = w4[base + 256];
    f4v a2 = w4[base + 512];
    f4v a3 = w4[base + 768];
    f4v a4 = w4[base + 1024];
    f4v a5 = w4[base + 1280];
    f4v a6 = w4[base + 1536];
    f4v a7 = w4[base + 1792];
    f4v r;
    QSEL(a0.x, r.x); QSEL(a0.y, r.y); QSEL(a0.z, r.z); QSEL(a0.w, r.w);
    __builtin_nontemporal_store(r, &o4[base]);
    QSEL(a1.x, r.x); QSEL(a1.y, r.y); QSEL(a1.z, r.z); QSEL(a1.w, r.w);
    __builtin_nontemporal_store(r, &o4[base + 256]);
    QSEL(a2.x, r.x); QSEL(a2.y, r.y); QSEL(a2.z, r.z); QSEL(a2.w, r.w);
    __builtin_nontemporal_store(r, &o4[base + 512]);
    QSEL(a3.x, r.x); QSEL(a3.y, r.y); QSEL(a3.z, r.z); QSEL(a3.w, r.w);
    __builtin_nontemporal_store(r, &o4[base + 768]);
    QSEL(a4.x, r.x); QSEL(a4.y, r.y); QSEL(a4.z, r.z); QSEL(a4.w, r.w);
    __builtin_nontemporal_store(r, &o4[base + 1024]);
    QSEL(a5.x, r.x); QSEL(a5.y, r.y); QSEL(a5.z, r.z); QSEL(a5.w, r.w);
    __builtin_nontemporal_store(r, &o4[base + 1280]);
    QSEL(a6.x, r.x); QSEL(a6.y, r.y); QSEL(a6.z, r.z); QSEL(a6.w, r.w);
    __builtin_nontemporal_store(r, &o4[base + 1536]);
    QSEL(a7.x, r.x); QSEL(a7.y, r.y); QSEL(a7.z, r.z); QSEL(a7.w, r.w);
    __builtin_nontemporal_store(r, &o4[base + 1792]);
}

// ---- generic-n fallback quantize (round 11, verified) ----
__global__ __launch_bounds__(THREADS) void quantize_g(const f4v* __restrict__ w4,
                                                      f4v* __restrict__ o4,
                                                      const float* __restrict__ bout0,
                                                      const float* __restrict__ bout1,
                                                      const float* __restrict__ alpha_ptr,
                                                      long long n, int nb) {
    #pragma clang fp contract(off)
    __shared__ float wsA[4], wsB[4];
    __shared__ float sP[2];
    __shared__ float sT[15];
    __shared__ float sC[16];
    {
        int i0 = threadIdx.x * 8;
        float v = 0.0f, u = 0.0f;
        if (i0 + 7 < nb) {
            const float* p0 = bout0 + i0;
            const float* p1 = bout1 + i0;
            v = ((p0[0] + p0[1]) + (p0[2] + p0[3])) + ((p0[4] + p0[5]) + (p0[6] + p0[7]));
            u = ((p1[0] + p1[1]) + (p1[2] + p1[3])) + ((p1[4] + p1[5]) + (p1[6] + p1[7]));
        }
        v = tree64(v);
        u = tree64(u);
        if ((threadIdx.x & 63) == 0) { wsA[threadIdx.x >> 6] = v; wsB[threadIdx.x >> 6] = u; }
        __syncthreads();
        if (threadIdx.x == 0) {
            sP[0] = ((wsA[0] + wsA[1]) + (wsA[2] + wsA[3])) / (float)n;
            sP[1] = sqrtf(((wsB[0] + wsB[1]) + (wsB[2] + wsB[3])) / (float)(n - 1));
        }
        __syncthreads();
    }
    {
        const float sd = sP[1];
        const float al = alpha_ptr[0];
        THRESH_SETUP(threadIdx.x)
    }
    __syncthreads();

    const float mean = sgpr_bcast(sP[0]);
    HOIST_TC()

    long long n4     = n >> 2;
    long long tid    = (long long)blockIdx.x * THREADS + threadIdx.x;
    long long stride = (long long)gridDim.x * THREADS;
    long long i = tid;
    for (; i + stride < n4; i += 2 * stride) {
        f4v a = w4[i];
        f4v b = w4[i + stride];
        f4v ra, rb;
        QSEL(a.x, ra.x); QSEL(a.y, ra.y); QSEL(a.z, ra.z); QSEL(a.w, ra.w);
        QSEL(b.x, rb.x); QSEL(b.y, rb.y); QSEL(b.z, rb.z); QSEL(b.w, rb.w);
        __builtin_nontemporal_store(ra, &o4[i]);
        __builtin_nontemporal_store(rb, &o4[i + stride]);
    }
    for (; i < n4; i += stride) {
        f4v a = w4[i];
        f4v ra;
        QSEL(a.x, ra.x); QSEL(a.y, ra.y); QSEL(a.z, ra.z); QSEL(a.w, ra.w);
        __builtin_nontemporal_store(ra, &o4[i]);
    }
}

extern "C" void kernel_launch(void* const* d_in, const int* in_sizes, int n_in,
                              void* d_out, int out_size, void* d_ws, size_t ws_size,
                              hipStream_t stream) {
    const float* w     = (const float*)d_in[0];
    const float* alpha = (const float*)d_in[1];
    float* out = (float*)d_out;
    long long n = (long long)in_sizes[0];          // 16777216 = 2^24

    int nblk = (int)(n >> 13);                     // 8192 elems/block -> 2048 blocks
    float* bout0 = (float*)d_ws;                   // nblk partials (sum)
    float* bout1 = bout0 + nblk;                   // nblk partials (sumsq)

    leaf_pass<0, 0><<<nblk, THREADS, 0, stream>>>(w, nullptr, bout0, n, nblk);
    leaf_pass<1, 1><<<nblk, THREADS, 0, stream>>>(w, bout0, bout1, n, nblk);
    if (n == (1LL << 24)) {
        quantize_b<<<nblk, THREADS, 0, stream>>>((const f4v*)w, (f4v*)out,
                                                 bout0, bout1, alpha, n, nblk);
    } else {
        quantize_g<<<2048, THREADS, 0, stream>>>((const f4v*)w, (f4v*)out,
                                                 bout0, bout1, alpha, n, nblk);
    }
}